// Round 1
// baseline (1688.342 us; speedup 1.0000x reference)
//
#include <hip/hip_runtime.h>
#include <cstdint>
#include <cstddef>

#define DIM 128
#define BN_EPS_ 1e-5f

// ---------------- BN stats: h = x*imp, accumulate per-feature sum/sumsq ----------------
__global__ __launch_bounds__(256) void k_mul_stats(
    const float* __restrict__ x, const float* __restrict__ imp,
    float* __restrict__ h0, float* __restrict__ gsum, float* __restrict__ gsq, int N)
{
    __shared__ float ls[256], lq[256];
    int t = threadIdx.x;
    int f = t & 127;
    int rs = t >> 7;
    float s = 0.f, q = 0.f;
    for (int r = blockIdx.x * 2 + rs; r < N; r += gridDim.x * 2) {
        float v = x[(size_t)r * DIM + f] * imp[r];
        h0[(size_t)r * DIM + f] = v;
        s += v; q += v * v;
    }
    ls[t] = s; lq[t] = q;
    __syncthreads();
    if (t < 128) {
        atomicAdd(&gsum[f], ls[t] + ls[t + 128]);
        atomicAdd(&gsq[f],  lq[t] + lq[t + 128]);
    }
}

__global__ void k_finalize(const float* __restrict__ gsum, const float* __restrict__ gsq,
                           const float* __restrict__ gamma, const float* __restrict__ beta,
                           float* __restrict__ scale, float* __restrict__ shift, int N)
{
    int f = threadIdx.x;
    float mean = gsum[f] / (float)N;
    float var  = gsq[f] / (float)N - mean * mean;
    var = fmaxf(var, 0.f);
    float sc = gamma[f] * rsqrtf(var + BN_EPS_);
    scale[f] = sc;
    shift[f] = beta[f] - mean * sc;
}

__global__ __launch_bounds__(256) void k_bn_apply(
    float* __restrict__ h0, const float* __restrict__ scale,
    const float* __restrict__ shift, int n4)
{
    int i = blockIdx.x * 256 + threadIdx.x;
    if (i >= n4) return;
    int f4 = i & 31;
    float4 v  = ((float4*)h0)[i];
    float4 sc = ((const float4*)scale)[f4];
    float4 sh = ((const float4*)shift)[f4];
    v.x = fmaf(v.x, sc.x, sh.x);
    v.y = fmaf(v.y, sc.y, sh.y);
    v.z = fmaf(v.z, sc.z, sh.z);
    v.w = fmaf(v.w, sc.w, sh.w);
    ((float4*)h0)[i] = v;
}

// ---------------- CSR build ----------------
__global__ void k_hist(const int* __restrict__ dst, int* __restrict__ deg, int E)
{
    int e = blockIdx.x * 256 + threadIdx.x;
    if (e < E) atomicAdd(&deg[dst[e]], 1);
}

__global__ __launch_bounds__(256) void k_chunksum(const int* __restrict__ deg, int* __restrict__ csum, int N)
{
    __shared__ int s[256];
    int t = threadIdx.x;
    int i = blockIdx.x * 256 + t;
    s[t] = (i < N) ? deg[i] : 0;
    __syncthreads();
    for (int off = 128; off > 0; off >>= 1) {
        if (t < off) s[t] += s[t + off];
        __syncthreads();
    }
    if (t == 0) csum[blockIdx.x] = s[0];
}

__global__ void k_scanchunks(int* __restrict__ csum, int* __restrict__ rstart, int nchunks, int N)
{
    __shared__ int s[512];
    int t = threadIdx.x;
    s[t] = (t < nchunks) ? csum[t] : 0;
    __syncthreads();
    for (int off = 1; off < 512; off <<= 1) {
        int add = (t >= off) ? s[t - off] : 0;
        __syncthreads();
        s[t] += add;
        __syncthreads();
    }
    if (t < nchunks) csum[t] = (t > 0) ? s[t - 1] : 0;  // exclusive chunk offsets
    if (t == 511) rstart[N] = s[511];                   // total = E
}

__global__ __launch_bounds__(256) void k_scanwithin(
    const int* __restrict__ deg, const int* __restrict__ csum,
    int* __restrict__ rstart, int* __restrict__ cursor, int N)
{
    __shared__ int s[256];
    int t = threadIdx.x;
    int i = blockIdx.x * 256 + t;
    int v = (i < N) ? deg[i] : 0;
    s[t] = v;
    __syncthreads();
    for (int off = 1; off < 256; off <<= 1) {
        int add = (t >= off) ? s[t - off] : 0;
        __syncthreads();
        s[t] += add;
        __syncthreads();
    }
    if (i < N) {
        int rs = csum[blockIdx.x] + s[t] - v;  // exclusive
        rstart[i] = rs;
        cursor[i] = rs;
    }
}

__global__ void k_scatter(const int* __restrict__ src, const int* __restrict__ dst,
                          int* __restrict__ cursor, int* __restrict__ csr, int E)
{
    int e = blockIdx.x * 256 + threadIdx.x;
    if (e < E) {
        int d = dst[e];
        int pos = atomicAdd(&cursor[d], 1);
        csr[pos] = src[e];
    }
}

// ---------------- per-node aggregation (pull over CSR): one wave per node ----------------
__global__ __launch_bounds__(256) void k_agg(
    const float* __restrict__ hin, int ldin,
    const int* __restrict__ rstart, const int* __restrict__ csr,
    float* __restrict__ agg, int N)
{
    int node = blockIdx.x * 4 + (threadIdx.x >> 6);
    if (node >= N) return;
    int lane = threadIdx.x & 63;
    int beg = rstart[node], end = rstart[node + 1];
    float ax = 0.f, ay = 0.f;
    int e = beg;
    for (; e + 2 <= end; e += 2) {
        int s0 = csr[e], s1 = csr[e + 1];
        float2 v0 = *(const float2*)(hin + (size_t)s0 * ldin + lane * 2);
        float2 v1 = *(const float2*)(hin + (size_t)s1 * ldin + lane * 2);
        ax += v0.x + v1.x;
        ay += v0.y + v1.y;
    }
    if (e < end) {
        int s0 = csr[e];
        float2 v0 = *(const float2*)(hin + (size_t)s0 * ldin + lane * 2);
        ax += v0.x; ay += v0.y;
    }
    float2 r; r.x = ax; r.y = ay;
    *(float2*)(agg + (size_t)node * DIM + lane * 2) = r;
}

// ---------------- fused (hin + agg) @ W + b -> tanh -> out slice ----------------
__global__ __launch_bounds__(256) void k_gemm(
    const float* __restrict__ hin, int ldin,
    const float* __restrict__ agg,
    const float* __restrict__ Wm,
    const float* __restrict__ bias,
    float* __restrict__ outp, int ldout,
    int N, int useAgg, int useBias)
{
    __shared__ float sW[DIM * DIM];  // 64 KiB
    int t = threadIdx.x;
#pragma unroll
    for (int i = 0; i < 16; ++i) {
        int idx = i * 1024 + t * 4;
        *(float4*)&sW[idx] = *(const float4*)&Wm[idx];
    }
    __syncthreads();

    int cg = t & 15, rg = t >> 4;
    int r0 = blockIdx.x * 64 + rg * 4;
    int c0 = cg * 8;
    float acc[4][8];
#pragma unroll
    for (int i = 0; i < 4; ++i)
#pragma unroll
        for (int j = 0; j < 8; ++j) acc[i][j] = 0.f;

    for (int k0 = 0; k0 < DIM; k0 += 4) {
        float4 a[4];
#pragma unroll
        for (int i = 0; i < 4; ++i) {
            int r = r0 + i;
            if (r < N) {
                float4 v = *(const float4*)&hin[(size_t)r * ldin + k0];
                if (useAgg) {
                    float4 g = *(const float4*)&agg[(size_t)r * DIM + k0];
                    v.x += g.x; v.y += g.y; v.z += g.z; v.w += g.w;
                }
                a[i] = v;
            } else {
                a[i] = make_float4(0.f, 0.f, 0.f, 0.f);
            }
        }
#pragma unroll
        for (int kk = 0; kk < 4; ++kk) {
            const float* wr = &sW[(k0 + kk) * DIM + c0];
            float4 w0 = *(const float4*)wr;
            float4 w1 = *(const float4*)(wr + 4);
#pragma unroll
            for (int i = 0; i < 4; ++i) {
                float ak = (kk == 0) ? a[i].x : (kk == 1) ? a[i].y : (kk == 2) ? a[i].z : a[i].w;
                acc[i][0] = fmaf(ak, w0.x, acc[i][0]);
                acc[i][1] = fmaf(ak, w0.y, acc[i][1]);
                acc[i][2] = fmaf(ak, w0.z, acc[i][2]);
                acc[i][3] = fmaf(ak, w0.w, acc[i][3]);
                acc[i][4] = fmaf(ak, w1.x, acc[i][4]);
                acc[i][5] = fmaf(ak, w1.y, acc[i][5]);
                acc[i][6] = fmaf(ak, w1.z, acc[i][6]);
                acc[i][7] = fmaf(ak, w1.w, acc[i][7]);
            }
        }
    }

    float b8[8];
#pragma unroll
    for (int j = 0; j < 8; ++j) b8[j] = useBias ? bias[c0 + j] : 0.f;

#pragma unroll
    for (int i = 0; i < 4; ++i) {
        int r = r0 + i;
        if (r < N) {
            float4 o0, o1;
            o0.x = tanhf(acc[i][0] + b8[0]);
            o0.y = tanhf(acc[i][1] + b8[1]);
            o0.z = tanhf(acc[i][2] + b8[2]);
            o0.w = tanhf(acc[i][3] + b8[3]);
            o1.x = tanhf(acc[i][4] + b8[4]);
            o1.y = tanhf(acc[i][5] + b8[5]);
            o1.z = tanhf(acc[i][6] + b8[6]);
            o1.w = tanhf(acc[i][7] + b8[7]);
            *(float4*)&outp[(size_t)r * ldout + c0]     = o0;
            *(float4*)&outp[(size_t)r * ldout + c0 + 4] = o1;
        }
    }
}

extern "C" void kernel_launch(void* const* d_in, const int* in_sizes, int n_in,
                              void* d_out, int out_size, void* d_ws, size_t ws_size,
                              hipStream_t stream)
{
    const float* x     = (const float*)d_in[0];
    const float* imp   = (const float*)d_in[1];
    const int*   eidx  = (const int*)d_in[2];
    const float* gamma = (const float*)d_in[3];
    const float* beta  = (const float*)d_in[4];
    const float* Wfc   = (const float*)d_in[5];
    const float* W[5]; const float* B[5];
    for (int i = 0; i < 5; ++i) {
        W[i] = (const float*)d_in[6 + 2 * i];
        B[i] = (const float*)d_in[7 + 2 * i];
    }
    float* out = (float*)d_out;

    const int N = in_sizes[0] / DIM;
    const int E = in_sizes[2] / 2;
    const int* src = eidx;
    const int* dst = eidx + E;

    char* ws = (char*)d_ws;
    size_t off = 0;
    auto alloc = [&](size_t b) -> char* {
        char* p = ws + off;
        off = (off + b + 255) & ~(size_t)255;
        return p;
    };
    float* h0     = (float*)alloc((size_t)N * DIM * 4);
    float* agg    = (float*)alloc((size_t)N * DIM * 4);
    int*   deg    = (int*)alloc((size_t)N * 4);
    int*   rstart = (int*)alloc((size_t)(N + 1) * 4);
    int*   cursor = (int*)alloc((size_t)N * 4);
    int*   csr    = (int*)alloc((size_t)E * 4);
    float* gsum   = (float*)alloc(128 * 4);
    float* gsq    = (float*)alloc(128 * 4);
    float* scale  = (float*)alloc(128 * 4);
    float* shift  = (float*)alloc(128 * 4);
    int*   csum   = (int*)alloc(4096 * 4);

    hipMemsetAsync(gsum, 0, 128 * 4, stream);
    hipMemsetAsync(gsq, 0, 128 * 4, stream);
    hipMemsetAsync(deg, 0, (size_t)N * 4, stream);

    k_mul_stats<<<1024, 256, 0, stream>>>(x, imp, h0, gsum, gsq, N);
    k_finalize<<<1, 128, 0, stream>>>(gsum, gsq, gamma, beta, scale, shift, N);
    k_bn_apply<<<(N * 32 + 255) / 256, 256, 0, stream>>>(h0, scale, shift, N * 32);

    k_hist<<<(E + 255) / 256, 256, 0, stream>>>(dst, deg, E);
    int nchunks = (N + 255) / 256;
    k_chunksum<<<nchunks, 256, 0, stream>>>(deg, csum, N);
    k_scanchunks<<<1, 512, 0, stream>>>(csum, rstart, nchunks, N);
    k_scanwithin<<<nchunks, 256, 0, stream>>>(deg, csum, rstart, cursor, N);
    k_scatter<<<(E + 255) / 256, 256, 0, stream>>>(src, dst, cursor, csr, E);

    for (int l = 0; l < 5; ++l) {
        const float* hin = (l == 0) ? h0 : out + (size_t)(l - 1) * DIM;
        int ldin = (l == 0) ? DIM : 6 * DIM;
        k_agg<<<(N + 3) / 4, 256, 0, stream>>>(hin, ldin, rstart, csr, agg, N);
        k_gemm<<<(N + 63) / 64, 256, 0, stream>>>(hin, ldin, agg, W[l], B[l],
                                                  out + (size_t)l * DIM, 6 * DIM, N, 1, 1);
    }
    k_gemm<<<(N + 63) / 64, 256, 0, stream>>>(out + (size_t)4 * DIM, 6 * DIM, nullptr, Wfc, nullptr,
                                              out + (size_t)5 * DIM, 6 * DIM, N, 0, 0);
}

// Round 3
// 1323.766 us; speedup vs baseline: 1.2754x; 1.2754x over previous
//
#include <hip/hip_runtime.h>
#include <hip/hip_fp16.h>
#include <cstdint>
#include <cstddef>

#define DIM 128
#define BN_EPS_ 1e-5f

typedef _Float16 half8 __attribute__((ext_vector_type(8)));
typedef float floatx4 __attribute__((ext_vector_type(4)));

__device__ __forceinline__ float fast_tanh(float x) {
    float t = __expf(2.f * x);
    return 1.f - 2.f / (t + 1.f);
}

// ---------------- BN stats: h = x*imp, accumulate per-feature sum/sumsq ----------------
__global__ __launch_bounds__(256) void k_mul_stats(
    const float* __restrict__ x, const float* __restrict__ imp,
    float* __restrict__ h0, float* __restrict__ gsum, float* __restrict__ gsq, int N)
{
    __shared__ float ls[256], lq[256];
    int t = threadIdx.x;
    int f = t & 127;
    int rs = t >> 7;
    float s = 0.f, q = 0.f;
    for (int r = blockIdx.x * 2 + rs; r < N; r += gridDim.x * 2) {
        float v = x[(size_t)r * DIM + f] * imp[r];
        h0[(size_t)r * DIM + f] = v;
        s += v; q += v * v;
    }
    ls[t] = s; lq[t] = q;
    __syncthreads();
    if (t < 128) {
        atomicAdd(&gsum[f], ls[t] + ls[t + 128]);
        atomicAdd(&gsq[f],  lq[t] + lq[t + 128]);
    }
}

__global__ void k_finalize(const float* __restrict__ gsum, const float* __restrict__ gsq,
                           const float* __restrict__ gamma, const float* __restrict__ beta,
                           float* __restrict__ scale, float* __restrict__ shift, int N)
{
    int f = threadIdx.x;
    float mean = gsum[f] / (float)N;
    float var  = gsq[f] / (float)N - mean * mean;
    var = fmaxf(var, 0.f);
    float sc = gamma[f] * rsqrtf(var + BN_EPS_);
    scale[f] = sc;
    shift[f] = beta[f] - mean * sc;
}

// normalize h0 (f32) -> (hi,lo) fp16 split
__global__ __launch_bounds__(256) void k_bn_apply(
    const float* __restrict__ h0,
    _Float16* __restrict__ hHi, _Float16* __restrict__ hLo,
    const float* __restrict__ scale, const float* __restrict__ shift, int n4)
{
    int i = blockIdx.x * 256 + threadIdx.x;
    if (i >= n4) return;
    int f4 = i & 31;
    float4 v  = ((const float4*)h0)[i];
    float4 sc = ((const float4*)scale)[f4];
    float4 sh = ((const float4*)shift)[f4];
    float h[4];
    h[0] = fmaf(v.x, sc.x, sh.x);
    h[1] = fmaf(v.y, sc.y, sh.y);
    h[2] = fmaf(v.z, sc.z, sh.z);
    h[3] = fmaf(v.w, sc.w, sh.w);
    _Float16 hi[4], lo[4];
#pragma unroll
    for (int j = 0; j < 4; ++j) {
        hi[j] = (_Float16)h[j];
        lo[j] = (_Float16)(h[j] - (float)hi[j]);
    }
    *(float2*)(hHi + (size_t)i * 4) = *(float2*)hi;
    *(float2*)(hLo + (size_t)i * 4) = *(float2*)lo;
}

// ---------------- weight split: Wt{Hi,Lo}[n][k] from f32 W[k][n] ----------------
__global__ __launch_bounds__(256) void k_wsplit(const float* __restrict__ W,
                                               _Float16* __restrict__ WtHi,
                                               _Float16* __restrict__ WtLo)
{
    for (int e = blockIdx.x * 256 + threadIdx.x; e < DIM * DIM; e += gridDim.x * 256) {
        int k = e >> 7, n = e & 127;
        float w = W[e];
        _Float16 hi = (_Float16)w;
        _Float16 lo = (_Float16)(w - (float)hi);
        WtHi[n * DIM + k] = hi;
        WtLo[n * DIM + k] = lo;
    }
}

// ---------------- CSR build ----------------
__global__ void k_hist(const int* __restrict__ dst, int* __restrict__ deg, int E)
{
    int e = blockIdx.x * 256 + threadIdx.x;
    if (e < E) atomicAdd(&deg[dst[e]], 1);
}

__global__ __launch_bounds__(256) void k_chunksum(const int* __restrict__ deg, int* __restrict__ csum, int N)
{
    __shared__ int s[256];
    int t = threadIdx.x;
    int i = blockIdx.x * 256 + t;
    s[t] = (i < N) ? deg[i] : 0;
    __syncthreads();
    for (int off = 128; off > 0; off >>= 1) {
        if (t < off) s[t] += s[t + off];
        __syncthreads();
    }
    if (t == 0) csum[blockIdx.x] = s[0];
}

__global__ void k_scanchunks(int* __restrict__ csum, int* __restrict__ rstart, int nchunks, int N)
{
    __shared__ int s[512];
    int t = threadIdx.x;
    s[t] = (t < nchunks) ? csum[t] : 0;
    __syncthreads();
    for (int off = 1; off < 512; off <<= 1) {
        int add = (t >= off) ? s[t - off] : 0;
        __syncthreads();
        s[t] += add;
        __syncthreads();
    }
    if (t < nchunks) csum[t] = (t > 0) ? s[t - 1] : 0;
    if (t == 511) rstart[N] = s[511];
}

__global__ __launch_bounds__(256) void k_scanwithin(
    const int* __restrict__ deg, const int* __restrict__ csum,
    int* __restrict__ rstart, int* __restrict__ cursor, int N)
{
    __shared__ int s[256];
    int t = threadIdx.x;
    int i = blockIdx.x * 256 + t;
    int v = (i < N) ? deg[i] : 0;
    s[t] = v;
    __syncthreads();
    for (int off = 1; off < 256; off <<= 1) {
        int add = (t >= off) ? s[t - off] : 0;
        __syncthreads();
        s[t] += add;
        __syncthreads();
    }
    if (i < N) {
        int rs = csum[blockIdx.x] + s[t] - v;
        rstart[i] = rs;
        cursor[i] = rs;
    }
}

__global__ void k_scatter(const int* __restrict__ src, const int* __restrict__ dst,
                          int* __restrict__ cursor, int* __restrict__ csr, int E)
{
    int e = blockIdx.x * 256 + threadIdx.x;
    if (e < E) {
        int d = dst[e];
        int pos = atomicAdd(&cursor[d], 1);
        csr[pos] = src[e];
    }
}

// ---------------- MFMA GEMM: Z = h @ W  (h = hi+lo, W = hi+lo; 3 products ≈ f32) ----------------
// block = 256 (4 waves); wave: 16 rows x 128 cols; block: 64 rows
__global__ __launch_bounds__(256) void k_gemmZ(
    const _Float16* __restrict__ Ahi, const _Float16* __restrict__ Alo,
    const _Float16* __restrict__ WtHi, const _Float16* __restrict__ WtLo,
    float* __restrict__ Zout,          // mode 0: [N][128]
    float* __restrict__ outF,          // mode 1: out slice, ld 768, tanh applied
    int N, int finalMode)
{
    int wave = threadIdx.x >> 6;
    int lane = threadIdx.x & 63;
    int r0 = blockIdx.x * 64 + wave * 16;
    int arow = r0 + (lane & 15);
    if (arow >= N) arow = N - 1;
    int kg = (lane >> 4) * 8;

    half8 ahi[4], alo[4];
#pragma unroll
    for (int ks = 0; ks < 4; ++ks) {
        ahi[ks] = *(const half8*)(Ahi + (size_t)arow * DIM + ks * 32 + kg);
        alo[ks] = *(const half8*)(Alo + (size_t)arow * DIM + ks * 32 + kg);
    }

    floatx4 acc[8];
#pragma unroll
    for (int nt = 0; nt < 8; ++nt) acc[nt] = (floatx4){0.f, 0.f, 0.f, 0.f};

#pragma unroll
    for (int nt = 0; nt < 8; ++nt) {
        int ncol = nt * 16 + (lane & 15);
#pragma unroll
        for (int ks = 0; ks < 4; ++ks) {
            half8 bhi = *(const half8*)(WtHi + (size_t)ncol * DIM + ks * 32 + kg);
            half8 blo = *(const half8*)(WtLo + (size_t)ncol * DIM + ks * 32 + kg);
            acc[nt] = __builtin_amdgcn_mfma_f32_16x16x32_f16(ahi[ks], bhi, acc[nt], 0, 0, 0);
            acc[nt] = __builtin_amdgcn_mfma_f32_16x16x32_f16(alo[ks], bhi, acc[nt], 0, 0, 0);
            acc[nt] = __builtin_amdgcn_mfma_f32_16x16x32_f16(ahi[ks], blo, acc[nt], 0, 0, 0);
        }
    }

    int rbase = r0 + (lane >> 4) * 4;
#pragma unroll
    for (int nt = 0; nt < 8; ++nt) {
        int col = nt * 16 + (lane & 15);
#pragma unroll
        for (int j = 0; j < 4; ++j) {
            int r = rbase + j;
            if (r < N) {
                if (finalMode) outF[(size_t)r * 768 + col] = fast_tanh(acc[nt][j]);
                else           Zout[(size_t)r * DIM + col] = acc[nt][j];
            }
        }
    }
}

// ---------------- fused aggregate + bias + tanh + split-store ----------------
// S = Z[node] + sum_j Z[j];  h = tanh(S + b); write out slice (f32) and (hi,lo) fp16
__global__ __launch_bounds__(256) void k_aggE(
    const float* __restrict__ Z,
    const int* __restrict__ rstart, const int* __restrict__ csr,
    const float* __restrict__ bias,
    float* __restrict__ outSlice,      // ld 768
    _Float16* __restrict__ hHi, _Float16* __restrict__ hLo, int N)
{
    int grp  = threadIdx.x >> 5;       // 8 nodes per block
    int lane = threadIdx.x & 31;       // 32 lanes x float4 = 512B row
    int node = blockIdx.x * 8 + grp;
    if (node >= N) return;
    int beg = rstart[node], end = rstart[node + 1];

    float4 s = *(const float4*)(Z + (size_t)node * DIM + lane * 4);
    int e = beg;
    for (; e + 2 <= end; e += 2) {
        int n0 = csr[e], n1 = csr[e + 1];
        float4 a = *(const float4*)(Z + (size_t)n0 * DIM + lane * 4);
        float4 b = *(const float4*)(Z + (size_t)n1 * DIM + lane * 4);
        s.x += a.x + b.x; s.y += a.y + b.y;
        s.z += a.z + b.z; s.w += a.w + b.w;
    }
    if (e < end) {
        int n0 = csr[e];
        float4 a = *(const float4*)(Z + (size_t)n0 * DIM + lane * 4);
        s.x += a.x; s.y += a.y; s.z += a.z; s.w += a.w;
    }

    float4 b4 = ((const float4*)bias)[lane];
    float h[4];
    h[0] = fast_tanh(s.x + b4.x);
    h[1] = fast_tanh(s.y + b4.y);
    h[2] = fast_tanh(s.z + b4.z);
    h[3] = fast_tanh(s.w + b4.w);

    *(float4*)(outSlice + (size_t)node * 768 + lane * 4) = make_float4(h[0], h[1], h[2], h[3]);

    _Float16 hi[4], lo[4];
#pragma unroll
    for (int j = 0; j < 4; ++j) {
        hi[j] = (_Float16)h[j];
        lo[j] = (_Float16)(h[j] - (float)hi[j]);
    }
    *(float2*)(hHi + (size_t)node * DIM + lane * 4) = *(float2*)hi;
    *(float2*)(hLo + (size_t)node * DIM + lane * 4) = *(float2*)lo;
}

extern "C" void kernel_launch(void* const* d_in, const int* in_sizes, int n_in,
                              void* d_out, int out_size, void* d_ws, size_t ws_size,
                              hipStream_t stream)
{
    const float* x     = (const float*)d_in[0];
    const float* imp   = (const float*)d_in[1];
    const int*   eidx  = (const int*)d_in[2];
    const float* gamma = (const float*)d_in[3];
    const float* beta  = (const float*)d_in[4];
    const float* Wfc   = (const float*)d_in[5];
    const float* W[5]; const float* B[5];
    for (int i = 0; i < 5; ++i) {
        W[i] = (const float*)d_in[6 + 2 * i];
        B[i] = (const float*)d_in[7 + 2 * i];
    }
    float* out = (float*)d_out;

    const int N = in_sizes[0] / DIM;
    const int E = in_sizes[2] / 2;
    const int* src = eidx;
    const int* dst = eidx + E;

    char* ws = (char*)d_ws;
    size_t off = 0;
    auto alloc = [&](size_t b) -> char* {
        char* p = ws + off;
        off = (off + b + 255) & ~(size_t)255;
        return p;
    };
    float*    h0   = (float*)alloc((size_t)N * DIM * 4);
    float*    Z    = (float*)alloc((size_t)N * DIM * 4);
    _Float16* hHi  = (_Float16*)alloc((size_t)N * DIM * 2);
    _Float16* hLo  = (_Float16*)alloc((size_t)N * DIM * 2);
    _Float16* WtHi[6]; _Float16* WtLo[6];
    for (int i = 0; i < 6; ++i) {
        WtHi[i] = (_Float16*)alloc(DIM * DIM * 2);
        WtLo[i] = (_Float16*)alloc(DIM * DIM * 2);
    }
    int*   deg    = (int*)alloc((size_t)N * 4);
    int*   rstart = (int*)alloc((size_t)(N + 1) * 4);
    int*   cursor = (int*)alloc((size_t)N * 4);
    int*   csr    = (int*)alloc((size_t)E * 4);
    float* gsum   = (float*)alloc(128 * 4);
    float* gsq    = (float*)alloc(128 * 4);
    float* scale  = (float*)alloc(128 * 4);
    float* shift  = (float*)alloc(128 * 4);
    int*   csum   = (int*)alloc(4096 * 4);

    hipMemsetAsync(gsum, 0, 128 * 4, stream);
    hipMemsetAsync(gsq, 0, 128 * 4, stream);
    hipMemsetAsync(deg, 0, (size_t)N * 4, stream);

    k_mul_stats<<<1024, 256, 0, stream>>>(x, imp, h0, gsum, gsq, N);
    k_finalize<<<1, 128, 0, stream>>>(gsum, gsq, gamma, beta, scale, shift, N);
    k_bn_apply<<<(N * 32 + 255) / 256, 256, 0, stream>>>(h0, hHi, hLo, scale, shift, N * 32);

    k_hist<<<(E + 255) / 256, 256, 0, stream>>>(dst, deg, E);
    int nchunks = (N + 255) / 256;
    k_chunksum<<<nchunks, 256, 0, stream>>>(deg, csum, N);
    k_scanchunks<<<1, 512, 0, stream>>>(csum, rstart, nchunks, N);
    k_scanwithin<<<nchunks, 256, 0, stream>>>(deg, csum, rstart, cursor, N);
    k_scatter<<<(E + 255) / 256, 256, 0, stream>>>(src, dst, cursor, csr, E);

    for (int i = 0; i < 5; ++i)
        k_wsplit<<<8, 256, 0, stream>>>(W[i], WtHi[i], WtLo[i]);
    k_wsplit<<<8, 256, 0, stream>>>(Wfc, WtHi[5], WtLo[5]);

    for (int l = 0; l < 5; ++l) {
        k_gemmZ<<<(N + 63) / 64, 256, 0, stream>>>(hHi, hLo, WtHi[l], WtLo[l],
                                                   Z, nullptr, N, 0);
        k_aggE<<<(N + 7) / 8, 256, 0, stream>>>(Z, rstart, csr, B[l],
                                                out + (size_t)l * DIM, hHi, hLo, N);
    }
    k_gemmZ<<<(N + 63) / 64, 256, 0, stream>>>(hHi, hLo, WtHi[5], WtLo[5],
                                               nullptr, out + (size_t)5 * DIM, N, 1);
}

// Round 5
// 1161.328 us; speedup vs baseline: 1.4538x; 1.1399x over previous
//
#include <hip/hip_runtime.h>
#include <hip/hip_fp16.h>
#include <cstdint>
#include <cstddef>

#define DIM 128
#define BN_EPS_ 1e-5f

typedef _Float16 half8 __attribute__((ext_vector_type(8)));
typedef float floatx4 __attribute__((ext_vector_type(4)));
typedef short shortx8 __attribute__((ext_vector_type(8)));

#define SCALE_H 32768.f
#define INV_H   (1.f/32768.f)

__device__ __forceinline__ float fast_tanh(float x) {
    float t = __expf(2.f * x);
    return 1.f - 2.f / (t + 1.f);
}

__device__ __forceinline__ short quant(float v, float scale) {
    int q = __float2int_rn(v * scale);
    q = max(min(q, 32767), -32767);
    return (short)q;
}

// ---------------- BN stats: accumulate per-feature sum/sumsq of x*imp ----------------
__global__ __launch_bounds__(256) void k_mul_stats(
    const float* __restrict__ x, const float* __restrict__ imp,
    float* __restrict__ gsum, float* __restrict__ gsq, int N)
{
    __shared__ float ls[256], lq[256];
    int t = threadIdx.x;
    int f = t & 127;
    int rs = t >> 7;
    float s = 0.f, q = 0.f;
    for (int r = blockIdx.x * 2 + rs; r < N; r += gridDim.x * 2) {
        float v = x[(size_t)r * DIM + f] * imp[r];
        s += v; q += v * v;
    }
    ls[t] = s; lq[t] = q;
    __syncthreads();
    if (t < 128) {
        atomicAdd(&gsum[f], ls[t] + ls[t + 128]);
        atomicAdd(&gsq[f],  lq[t] + lq[t + 128]);
    }
}

__global__ void k_finalize(const float* __restrict__ gsum, const float* __restrict__ gsq,
                           const float* __restrict__ gamma, const float* __restrict__ beta,
                           float* __restrict__ scale, float* __restrict__ shift, int N)
{
    int f = threadIdx.x;
    float mean = gsum[f] / (float)N;
    float var  = gsq[f] / (float)N - mean * mean;
    var = fmaxf(var, 0.f);
    float sc = gamma[f] * rsqrtf(var + BN_EPS_);
    scale[f] = sc;
    shift[f] = beta[f] - mean * sc;
}

// BN apply -> f32 h0 (layer-0 h is unbounded: no quantization!)
__global__ __launch_bounds__(256) void k_bn_apply(
    const float* __restrict__ x, const float* __restrict__ imp,
    const float* __restrict__ scale, const float* __restrict__ shift,
    float* __restrict__ h0, int n32)
{
    int i = blockIdx.x * 256 + threadIdx.x;
    if (i >= n32) return;
    int r = i >> 5, f4 = i & 31;
    float im = imp[r];
    float4 v  = ((const float4*)x)[i];
    float4 sc = ((const float4*)scale)[f4];
    float4 sh = ((const float4*)shift)[f4];
    float4 o;
    o.x = fmaf(v.x * im, sc.x, sh.x);
    o.y = fmaf(v.y * im, sc.y, sh.y);
    o.z = fmaf(v.z * im, sc.z, sh.z);
    o.w = fmaf(v.w * im, sc.w, sh.w);
    ((float4*)h0)[i] = o;
}

// ---------------- weight split: Wt{Hi,Lo}[n][k] from f32 W[k][n] ----------------
__global__ __launch_bounds__(256) void k_wsplit(const float* __restrict__ W,
                                               _Float16* __restrict__ WtHi,
                                               _Float16* __restrict__ WtLo)
{
    for (int e = blockIdx.x * 256 + threadIdx.x; e < DIM * DIM; e += gridDim.x * 256) {
        int k = e >> 7, n = e & 127;
        float w = W[e];
        _Float16 hi = (_Float16)w;
        _Float16 lo = (_Float16)(w - (float)hi);
        WtHi[n * DIM + k] = hi;
        WtLo[n * DIM + k] = lo;
    }
}

// ---------------- CSR build ----------------
__global__ void k_hist(const int* __restrict__ dst, int* __restrict__ deg, int E)
{
    int e = blockIdx.x * 256 + threadIdx.x;
    if (e < E) atomicAdd(&deg[dst[e]], 1);
}

__global__ __launch_bounds__(256) void k_chunksum(const int* __restrict__ deg, int* __restrict__ csum, int N)
{
    __shared__ int s[256];
    int t = threadIdx.x;
    int i = blockIdx.x * 256 + t;
    s[t] = (i < N) ? deg[i] : 0;
    __syncthreads();
    for (int off = 128; off > 0; off >>= 1) {
        if (t < off) s[t] += s[t + off];
        __syncthreads();
    }
    if (t == 0) csum[blockIdx.x] = s[0];
}

__global__ void k_scanchunks(int* __restrict__ csum, int* __restrict__ rstart, int nchunks, int N)
{
    __shared__ int s[512];
    int t = threadIdx.x;
    s[t] = (t < nchunks) ? csum[t] : 0;
    __syncthreads();
    for (int off = 1; off < 512; off <<= 1) {
        int add = (t >= off) ? s[t - off] : 0;
        __syncthreads();
        s[t] += add;
        __syncthreads();
    }
    if (t < nchunks) csum[t] = (t > 0) ? s[t - 1] : 0;
    if (t == 511) rstart[N] = s[511];
}

__global__ __launch_bounds__(256) void k_scanwithin(
    const int* __restrict__ deg, const int* __restrict__ csum,
    int* __restrict__ rstart, int* __restrict__ cursor, int N)
{
    __shared__ int s[256];
    int t = threadIdx.x;
    int i = blockIdx.x * 256 + t;
    int v = (i < N) ? deg[i] : 0;
    s[t] = v;
    __syncthreads();
    for (int off = 1; off < 256; off <<= 1) {
        int add = (t >= off) ? s[t - off] : 0;
        __syncthreads();
        s[t] += add;
        __syncthreads();
    }
    if (i < N) {
        int rs = csum[blockIdx.x] + s[t] - v;
        rstart[i] = rs;
        cursor[i] = rs;
    }
}

__global__ void k_scatter(const int* __restrict__ src, const int* __restrict__ dst,
                          int* __restrict__ cursor, int* __restrict__ csr, int E)
{
    int e = blockIdx.x * 256 + threadIdx.x;
    if (e < E) {
        int d = dst[e];
        int pos = atomicAdd(&cursor[d], 1);
        csr[pos] = src[e];
    }
}

// ---------------- layer-1 aggregation over f32 h0 (exact path) ----------------
// 32 lanes per node, float4 per lane (512B rows)
__global__ __launch_bounds__(256) void k_aggF(
    const float* __restrict__ h0,
    const int* __restrict__ rstart, const int* __restrict__ csr,
    float* __restrict__ S, int N)
{
    int node = blockIdx.x * 8 + (threadIdx.x >> 5);
    if (node >= N) return;
    int lane = threadIdx.x & 31;
    int beg = rstart[node], end = rstart[node + 1];

    float4 s = *(const float4*)(h0 + (size_t)node * DIM + lane * 4);
    int e = beg;
    for (; e + 2 <= end; e += 2) {
        int n0 = csr[e], n1 = csr[e + 1];
        float4 a = *(const float4*)(h0 + (size_t)n0 * DIM + lane * 4);
        float4 b = *(const float4*)(h0 + (size_t)n1 * DIM + lane * 4);
        s.x += a.x + b.x; s.y += a.y + b.y;
        s.z += a.z + b.z; s.w += a.w + b.w;
    }
    if (e < end) {
        float4 a = *(const float4*)(h0 + (size_t)csr[e] * DIM + lane * 4);
        s.x += a.x; s.y += a.y; s.z += a.z; s.w += a.w;
    }
    *(float4*)(S + (size_t)node * DIM + lane * 4) = s;
}

// ---------------- layers 2..5 aggregation: exact int32 sum of int16 h ----------------
// 16 lanes per node, 16B (8 x int16) per lane; 4-deep unrolled gather
__global__ __launch_bounds__(256) void k_aggS(
    const short* __restrict__ hq,
    const int* __restrict__ rstart, const int* __restrict__ csr,
    float* __restrict__ S, float invScale, int N)
{
    int node = blockIdx.x * 16 + (threadIdx.x >> 4);
    if (node >= N) return;
    int l16 = threadIdx.x & 15;
    const shortx8* base = (const shortx8*)hq;

    int beg = rstart[node], end = rstart[node + 1];

    shortx8 sv = base[(size_t)node * 16 + l16];
    int acc[8];
#pragma unroll
    for (int j = 0; j < 8; ++j) acc[j] = (int)sv[j];

    int e = beg;
    for (; e + 4 <= end; e += 4) {
        int n0 = csr[e], n1 = csr[e + 1], n2 = csr[e + 2], n3 = csr[e + 3];
        shortx8 v0 = base[(size_t)n0 * 16 + l16];
        shortx8 v1 = base[(size_t)n1 * 16 + l16];
        shortx8 v2 = base[(size_t)n2 * 16 + l16];
        shortx8 v3 = base[(size_t)n3 * 16 + l16];
#pragma unroll
        for (int j = 0; j < 8; ++j)
            acc[j] += ((int)v0[j] + (int)v1[j]) + ((int)v2[j] + (int)v3[j]);
    }
    for (; e < end; ++e) {
        shortx8 v0 = base[(size_t)csr[e] * 16 + l16];
#pragma unroll
        for (int j = 0; j < 8; ++j) acc[j] += (int)v0[j];
    }

    float4 o0, o1;
    o0.x = acc[0] * invScale; o0.y = acc[1] * invScale;
    o0.z = acc[2] * invScale; o0.w = acc[3] * invScale;
    o1.x = acc[4] * invScale; o1.y = acc[5] * invScale;
    o1.z = acc[6] * invScale; o1.w = acc[7] * invScale;
    float* dp = S + (size_t)node * DIM + l16 * 8;
    *(float4*)dp = o0;
    *(float4*)(dp + 4) = o1;
}

// ---------------- MFMA GEMM: t = tanh(A @ W + b); A f32 (ld param), split hi/lo in-reg ----
__global__ __launch_bounds__(256) void k_gemmT(
    const float* __restrict__ A, int lda,
    const _Float16* __restrict__ WtHi, const _Float16* __restrict__ WtLo,
    const float* __restrict__ bias,      // may be null
    float* __restrict__ outSlice,        // ld 768
    short* __restrict__ hqNext,          // may be null
    int N)
{
    int wave = threadIdx.x >> 6;
    int lane = threadIdx.x & 63;
    int r0 = blockIdx.x * 64 + wave * 16;
    int arow = r0 + (lane & 15);
    if (arow >= N) arow = N - 1;
    int kg = (lane >> 4) * 8;

    half8 ahi[4], alo[4];
#pragma unroll
    for (int ks = 0; ks < 4; ++ks) {
        const float* ap = A + (size_t)arow * lda + ks * 32 + kg;
        float4 f0 = *(const float4*)ap;
        float4 f1 = *(const float4*)(ap + 4);
        float fv[8] = {f0.x, f0.y, f0.z, f0.w, f1.x, f1.y, f1.z, f1.w};
#pragma unroll
        for (int j = 0; j < 8; ++j) {
            _Float16 h = (_Float16)fv[j];
            ahi[ks][j] = h;
            alo[ks][j] = (_Float16)(fv[j] - (float)h);
        }
    }

    floatx4 acc[8];
#pragma unroll
    for (int nt = 0; nt < 8; ++nt) acc[nt] = (floatx4){0.f, 0.f, 0.f, 0.f};

#pragma unroll
    for (int nt = 0; nt < 8; ++nt) {
        int ncol = nt * 16 + (lane & 15);
#pragma unroll
        for (int ks = 0; ks < 4; ++ks) {
            half8 bhi = *(const half8*)(WtHi + (size_t)ncol * DIM + ks * 32 + kg);
            half8 blo = *(const half8*)(WtLo + (size_t)ncol * DIM + ks * 32 + kg);
            acc[nt] = __builtin_amdgcn_mfma_f32_16x16x32_f16(ahi[ks], bhi, acc[nt], 0, 0, 0);
            acc[nt] = __builtin_amdgcn_mfma_f32_16x16x32_f16(alo[ks], bhi, acc[nt], 0, 0, 0);
            acc[nt] = __builtin_amdgcn_mfma_f32_16x16x32_f16(ahi[ks], blo, acc[nt], 0, 0, 0);
        }
    }

    int rbase = r0 + (lane >> 4) * 4;
#pragma unroll
    for (int nt = 0; nt < 8; ++nt) {
        int col = nt * 16 + (lane & 15);
        float bv = bias ? bias[col] : 0.f;
#pragma unroll
        for (int j = 0; j < 4; ++j) {
            int r = rbase + j;
            if (r < N) {
                float t = fast_tanh(acc[nt][j] + bv);
                outSlice[(size_t)r * 768 + col] = t;
                if (hqNext) hqNext[(size_t)r * DIM + col] = quant(t, SCALE_H);
            }
        }
    }
}

extern "C" void kernel_launch(void* const* d_in, const int* in_sizes, int n_in,
                              void* d_out, int out_size, void* d_ws, size_t ws_size,
                              hipStream_t stream)
{
    const float* x     = (const float*)d_in[0];
    const float* imp   = (const float*)d_in[1];
    const int*   eidx  = (const int*)d_in[2];
    const float* gamma = (const float*)d_in[3];
    const float* beta  = (const float*)d_in[4];
    const float* Wfc   = (const float*)d_in[5];
    const float* W[5]; const float* B[5];
    for (int i = 0; i < 5; ++i) {
        W[i] = (const float*)d_in[6 + 2 * i];
        B[i] = (const float*)d_in[7 + 2 * i];
    }
    float* out = (float*)d_out;

    const int N = in_sizes[0] / DIM;
    const int E = in_sizes[2] / 2;
    const int* src = eidx;
    const int* dst = eidx + E;

    char* ws = (char*)d_ws;
    size_t off = 0;
    auto alloc = [&](size_t b) -> char* {
        char* p = ws + off;
        off = (off + b + 255) & ~(size_t)255;
        return p;
    };
    float* h0     = (float*)alloc((size_t)N * DIM * 4);
    short* hq     = (short*)alloc((size_t)N * DIM * 2);
    float* S      = (float*)alloc((size_t)N * DIM * 4);
    _Float16* WtHi[6]; _Float16* WtLo[6];
    for (int i = 0; i < 6; ++i) {
        WtHi[i] = (_Float16*)alloc(DIM * DIM * 2);
        WtLo[i] = (_Float16*)alloc(DIM * DIM * 2);
    }
    int*   deg    = (int*)alloc((size_t)N * 4);
    int*   rstart = (int*)alloc((size_t)(N + 1) * 4);
    int*   cursor = (int*)alloc((size_t)N * 4);
    int*   csr    = (int*)alloc((size_t)E * 4);
    float* gsum   = (float*)alloc(128 * 4);
    float* gsq    = (float*)alloc(128 * 4);
    float* scale  = (float*)alloc(128 * 4);
    float* shift  = (float*)alloc(128 * 4);
    int*   csum   = (int*)alloc(4096 * 4);

    hipMemsetAsync(gsum, 0, 128 * 4, stream);
    hipMemsetAsync(gsq, 0, 128 * 4, stream);
    hipMemsetAsync(deg, 0, (size_t)N * 4, stream);

    // BN -> h0 (f32)
    k_mul_stats<<<1024, 256, 0, stream>>>(x, imp, gsum, gsq, N);
    k_finalize<<<1, 128, 0, stream>>>(gsum, gsq, gamma, beta, scale, shift, N);
    k_bn_apply<<<(N * 32 + 255) / 256, 256, 0, stream>>>(x, imp, scale, shift, h0, N * 32);

    // CSR
    k_hist<<<(E + 255) / 256, 256, 0, stream>>>(dst, deg, E);
    int nchunks = (N + 255) / 256;
    k_chunksum<<<nchunks, 256, 0, stream>>>(deg, csum, N);
    k_scanchunks<<<1, 512, 0, stream>>>(csum, rstart, nchunks, N);
    k_scanwithin<<<nchunks, 256, 0, stream>>>(deg, csum, rstart, cursor, N);
    k_scatter<<<(E + 255) / 256, 256, 0, stream>>>(src, dst, cursor, csr, E);

    // weights
    for (int i = 0; i < 5; ++i)
        k_wsplit<<<8, 256, 0, stream>>>(W[i], WtHi[i], WtLo[i]);
    k_wsplit<<<8, 256, 0, stream>>>(Wfc, WtHi[5], WtLo[5]);

    // layer 1: exact f32 aggregation of h0
    k_aggF<<<(N + 7) / 8, 256, 0, stream>>>(h0, rstart, csr, S, N);
    k_gemmT<<<(N + 63) / 64, 256, 0, stream>>>(S, DIM, WtHi[0], WtLo[0], B[0],
                                               out, hq, N);
    // layers 2..5: int16 h aggregation (exact int32 sums)
    for (int l = 1; l < 5; ++l) {
        k_aggS<<<(N + 15) / 16, 256, 0, stream>>>(hq, rstart, csr, S, INV_H, N);
        k_gemmT<<<(N + 63) / 64, 256, 0, stream>>>(S, DIM, WtHi[l], WtLo[l], B[l],
                                                   out + (size_t)l * DIM,
                                                   (l < 4) ? hq : nullptr, N);
    }
    // final: tanh(h5 @ Wfc), h5 = out slice 4 (ld 768)
    k_gemmT<<<(N + 63) / 64, 256, 0, stream>>>(out + (size_t)4 * DIM, 768,
                                               WtHi[5], WtLo[5], nullptr,
                                               out + (size_t)5 * DIM, nullptr, N);
}

// Round 6
// 1030.039 us; speedup vs baseline: 1.6391x; 1.1275x over previous
//
#include <hip/hip_runtime.h>
#include <hip/hip_fp16.h>
#include <cstdint>
#include <cstddef>

#define DIM 128
#define BN_EPS_ 1e-5f

typedef _Float16 half8 __attribute__((ext_vector_type(8)));
typedef float floatx4 __attribute__((ext_vector_type(4)));
typedef short shortx8 __attribute__((ext_vector_type(8)));

#define SCALE_H 32768.f
#define INV_H   (1.f/32768.f)

__device__ __forceinline__ float fast_tanh(float x) {
    float t = __expf(2.f * x);
    return 1.f - 2.f / (t + 1.f);
}

__device__ __forceinline__ short quant(float v, float scale) {
    int q = __float2int_rn(v * scale);
    q = max(min(q, 32767), -32767);
    return (short)q;
}

// ---------------- BN stats: per-feature sum/sumsq/maxabs of h' = x*imp ----------------
__global__ __launch_bounds__(256) void k_stats(
    const float* __restrict__ x, const float* __restrict__ imp,
    float* __restrict__ gsum, float* __restrict__ gsq, float* __restrict__ gmax, int N)
{
    __shared__ float ls[256], lq[256], lm[256];
    int t = threadIdx.x;
    int f = t & 127;
    int rs = t >> 7;
    float s = 0.f, q = 0.f, m = 0.f;
    for (int r = blockIdx.x * 2 + rs; r < N; r += gridDim.x * 2) {
        float v = x[(size_t)r * DIM + f] * imp[r];
        s += v; q += v * v; m = fmaxf(m, fabsf(v));
    }
    ls[t] = s; lq[t] = q; lm[t] = m;
    __syncthreads();
    if (t < 128) {
        atomicAdd(&gsum[f], ls[t] + ls[t + 128]);
        atomicAdd(&gsq[f],  lq[t] + lq[t + 128]);
        float mm = fmaxf(lm[t], lm[t + 128]);
        atomicMax((int*)&gmax[f], __float_as_int(mm));  // valid: mm >= 0
    }
}

// scale/shift per column + global quant bound Q -> q0[0]=32766/Q, q0[1]=Q/32766
__global__ void k_finalize(const float* __restrict__ gsum, const float* __restrict__ gsq,
                           const float* __restrict__ gmax,
                           const float* __restrict__ gamma, const float* __restrict__ beta,
                           float* __restrict__ scale, float* __restrict__ shift,
                           float* __restrict__ q0, int N)
{
    __shared__ float sb[128];
    int f = threadIdx.x;
    float mean = gsum[f] / (float)N;
    float var  = gsq[f] / (float)N - mean * mean;
    var = fmaxf(var, 0.f);
    float sc = gamma[f] * rsqrtf(var + BN_EPS_);
    float sh = beta[f] - mean * sc;
    scale[f] = sc;
    shift[f] = sh;
    sb[f] = fabsf(sc) * gmax[f] + fabsf(sh);   // bound on |h0| in this column
    __syncthreads();
    for (int off = 64; off > 0; off >>= 1) {
        if (f < off) sb[f] = fmaxf(sb[f], sb[f + off]);
        __syncthreads();
    }
    if (f == 0) {
        float Q = fmaxf(sb[0], 1e-20f);
        q0[0] = 32766.f / Q;
        q0[1] = Q / 32766.f;
    }
}

// BN apply + quantize with dynamic scale -> hq0 (int16, exact bound: no clipping)
__global__ __launch_bounds__(256) void k_bn_quant(
    const float* __restrict__ x, const float* __restrict__ imp,
    const float* __restrict__ scale, const float* __restrict__ shift,
    const float* __restrict__ q0, short* __restrict__ hq0, int n32)
{
    int i = blockIdx.x * 256 + threadIdx.x;
    if (i >= n32) return;
    float qs = q0[0];
    int r = i >> 5, f4 = i & 31;
    float im = imp[r];
    float4 v  = ((const float4*)x)[i];
    float4 sc = ((const float4*)scale)[f4];
    float4 sh = ((const float4*)shift)[f4];
    short q[4];
    q[0] = quant(fmaf(v.x * im, sc.x, sh.x), qs);
    q[1] = quant(fmaf(v.y * im, sc.y, sh.y), qs);
    q[2] = quant(fmaf(v.z * im, sc.z, sh.z), qs);
    q[3] = quant(fmaf(v.w * im, sc.w, sh.w), qs);
    *(float2*)(hq0 + (size_t)i * 4) = *(float2*)q;
}

// ---------------- weight split: Wt{Hi,Lo}[n][k] from f32 W[k][n] ----------------
__global__ __launch_bounds__(256) void k_wsplit(const float* __restrict__ W,
                                               _Float16* __restrict__ WtHi,
                                               _Float16* __restrict__ WtLo)
{
    for (int e = blockIdx.x * 256 + threadIdx.x; e < DIM * DIM; e += gridDim.x * 256) {
        int k = e >> 7, n = e & 127;
        float w = W[e];
        _Float16 hi = (_Float16)w;
        _Float16 lo = (_Float16)(w - (float)hi);
        WtHi[n * DIM + k] = hi;
        WtLo[n * DIM + k] = lo;
    }
}

// ---------------- CSR build ----------------
__global__ void k_hist(const int* __restrict__ dst, int* __restrict__ deg, int E)
{
    int e = blockIdx.x * 256 + threadIdx.x;
    if (e < E) atomicAdd(&deg[dst[e]], 1);
}

__global__ __launch_bounds__(256) void k_chunksum(const int* __restrict__ deg, int* __restrict__ csum, int N)
{
    __shared__ int s[256];
    int t = threadIdx.x;
    int i = blockIdx.x * 256 + t;
    s[t] = (i < N) ? deg[i] : 0;
    __syncthreads();
    for (int off = 128; off > 0; off >>= 1) {
        if (t < off) s[t] += s[t + off];
        __syncthreads();
    }
    if (t == 0) csum[blockIdx.x] = s[0];
}

__global__ void k_scanchunks(int* __restrict__ csum, int* __restrict__ rstart, int nchunks, int N)
{
    __shared__ int s[512];
    int t = threadIdx.x;
    s[t] = (t < nchunks) ? csum[t] : 0;
    __syncthreads();
    for (int off = 1; off < 512; off <<= 1) {
        int add = (t >= off) ? s[t - off] : 0;
        __syncthreads();
        s[t] += add;
        __syncthreads();
    }
    if (t < nchunks) csum[t] = (t > 0) ? s[t - 1] : 0;
    if (t == 511) rstart[N] = s[511];
}

__global__ __launch_bounds__(256) void k_scanwithin(
    const int* __restrict__ deg, const int* __restrict__ csum,
    int* __restrict__ rstart, int* __restrict__ cursor, int N)
{
    __shared__ int s[256];
    int t = threadIdx.x;
    int i = blockIdx.x * 256 + t;
    int v = (i < N) ? deg[i] : 0;
    s[t] = v;
    __syncthreads();
    for (int off = 1; off < 256; off <<= 1) {
        int add = (t >= off) ? s[t - off] : 0;
        __syncthreads();
        s[t] += add;
        __syncthreads();
    }
    if (i < N) {
        int rs = csum[blockIdx.x] + s[t] - v;
        rstart[i] = rs;
        cursor[i] = rs;
    }
}

__global__ void k_scatter(const int* __restrict__ src, const int* __restrict__ dst,
                          int* __restrict__ cursor, int* __restrict__ csr, int E)
{
    int e = blockIdx.x * 256 + threadIdx.x;
    if (e < E) {
        int d = dst[e];
        int pos = atomicAdd(&cursor[d], 1);
        csr[pos] = src[e];
    }
}

// ---------------- fused GIN layer: gather(int16)+int32 sum -> LDS -> MFMA -> tanh ----------
// block = 256 threads = 64 nodes. FINAL=1 additionally applies Wfc via LDS loopback.
template<int FINAL>
__global__ __launch_bounds__(256) void k_layer(
    const short* __restrict__ hqIn,
    const int* __restrict__ rstart, const int* __restrict__ csr,
    const float* __restrict__ invPtr, float invConst,
    const _Float16* __restrict__ WtHi, const _Float16* __restrict__ WtLo,
    const float* __restrict__ bias,
    const _Float16* __restrict__ WfHi, const _Float16* __restrict__ WfLo,
    float* __restrict__ outS,          // out + l*128, ld 768
    float* __restrict__ outF,          // out + 5*128 (FINAL only)
    short* __restrict__ hqOut,         // may be null
    int N)
{
    __shared__ float sA[64][132];      // pad 132: 2-way LDS conflicts only
    int t = threadIdx.x;
    float inv = invPtr ? invPtr[0] : invConst;

    // ---- phase A: aggregate 64 nodes (16 lanes/node, 16 nodes/pass, 4 passes) ----
    {
        int l16 = t & 15;
        int sg  = t >> 4;              // 0..15
        const shortx8* base = (const shortx8*)hqIn;
#pragma unroll
        for (int pass = 0; pass < 4; ++pass) {
            int nl = pass * 16 + sg;
            int node = blockIdx.x * 64 + nl;
            float* dstp = &sA[nl][l16 * 8];
            if (node < N) {
                int beg = rstart[node], end = rstart[node + 1];
                shortx8 sv = base[(size_t)node * 16 + l16];
                int acc[8];
#pragma unroll
                for (int j = 0; j < 8; ++j) acc[j] = (int)sv[j];
                int e = beg;
                for (; e + 4 <= end; e += 4) {
                    int n0 = csr[e], n1 = csr[e + 1], n2 = csr[e + 2], n3 = csr[e + 3];
                    shortx8 v0 = base[(size_t)n0 * 16 + l16];
                    shortx8 v1 = base[(size_t)n1 * 16 + l16];
                    shortx8 v2 = base[(size_t)n2 * 16 + l16];
                    shortx8 v3 = base[(size_t)n3 * 16 + l16];
#pragma unroll
                    for (int j = 0; j < 8; ++j)
                        acc[j] += ((int)v0[j] + (int)v1[j]) + ((int)v2[j] + (int)v3[j]);
                }
                for (; e < end; ++e) {
                    shortx8 v0 = base[(size_t)csr[e] * 16 + l16];
#pragma unroll
                    for (int j = 0; j < 8; ++j) acc[j] += (int)v0[j];
                }
#pragma unroll
                for (int j = 0; j < 8; ++j) dstp[j] = acc[j] * inv;
            } else {
#pragma unroll
                for (int j = 0; j < 8; ++j) dstp[j] = 0.f;
            }
        }
    }
    __syncthreads();

    // ---- phase B: per-wave 16x128 MFMA tile from LDS, hi/lo split ----
    int wave = t >> 6;
    int lane = t & 63;
    int kg = (lane >> 4) * 8;
    int arowL = wave * 16 + (lane & 15);

    half8 ahi[4], alo[4];
#pragma unroll
    for (int ks = 0; ks < 4; ++ks) {
        float4 f0 = *(const float4*)&sA[arowL][ks * 32 + kg];
        float4 f1 = *(const float4*)&sA[arowL][ks * 32 + kg + 4];
        float fv[8] = {f0.x, f0.y, f0.z, f0.w, f1.x, f1.y, f1.z, f1.w};
#pragma unroll
        for (int j = 0; j < 8; ++j) {
            _Float16 h = (_Float16)fv[j];
            ahi[ks][j] = h;
            alo[ks][j] = (_Float16)(fv[j] - (float)h);
        }
    }

    floatx4 acc[8];
#pragma unroll
    for (int nt = 0; nt < 8; ++nt) acc[nt] = (floatx4){0.f, 0.f, 0.f, 0.f};
#pragma unroll
    for (int nt = 0; nt < 8; ++nt) {
        int ncol = nt * 16 + (lane & 15);
#pragma unroll
        for (int ks = 0; ks < 4; ++ks) {
            half8 bhi = *(const half8*)(WtHi + (size_t)ncol * DIM + ks * 32 + kg);
            half8 blo = *(const half8*)(WtLo + (size_t)ncol * DIM + ks * 32 + kg);
            acc[nt] = __builtin_amdgcn_mfma_f32_16x16x32_f16(ahi[ks], bhi, acc[nt], 0, 0, 0);
            acc[nt] = __builtin_amdgcn_mfma_f32_16x16x32_f16(alo[ks], bhi, acc[nt], 0, 0, 0);
            acc[nt] = __builtin_amdgcn_mfma_f32_16x16x32_f16(ahi[ks], blo, acc[nt], 0, 0, 0);
        }
    }

    int rbaseL = wave * 16 + (lane >> 4) * 4;
    int rglob = blockIdx.x * 64 + rbaseL;
    float tv[8][4];
#pragma unroll
    for (int nt = 0; nt < 8; ++nt) {
        int col = nt * 16 + (lane & 15);
        float bv = bias[col];
#pragma unroll
        for (int j = 0; j < 4; ++j) {
            float tt = fast_tanh(acc[nt][j] + bv);
            tv[nt][j] = tt;
            int r = rglob + j;
            if (r < N) {
                outS[(size_t)r * 768 + col] = tt;
                if (hqOut) hqOut[(size_t)r * DIM + col] = quant(tt, SCALE_H);
            }
        }
    }

    if (FINAL) {
        // loop h5 tile back through LDS, apply Wfc
        __syncthreads();   // all waves have loaded their a-frags from sA
#pragma unroll
        for (int nt = 0; nt < 8; ++nt) {
            int col = nt * 16 + (lane & 15);
#pragma unroll
            for (int j = 0; j < 4; ++j)
                sA[rbaseL + j][col] = tv[nt][j];
        }
        __syncthreads();

        half8 chi[4], clo[4];
#pragma unroll
        for (int ks = 0; ks < 4; ++ks) {
            float4 f0 = *(const float4*)&sA[arowL][ks * 32 + kg];
            float4 f1 = *(const float4*)&sA[arowL][ks * 32 + kg + 4];
            float fv[8] = {f0.x, f0.y, f0.z, f0.w, f1.x, f1.y, f1.z, f1.w};
#pragma unroll
            for (int j = 0; j < 8; ++j) {
                _Float16 h = (_Float16)fv[j];
                chi[ks][j] = h;
                clo[ks][j] = (_Float16)(fv[j] - (float)h);
            }
        }
        floatx4 ac2[8];
#pragma unroll
        for (int nt = 0; nt < 8; ++nt) ac2[nt] = (floatx4){0.f, 0.f, 0.f, 0.f};
#pragma unroll
        for (int nt = 0; nt < 8; ++nt) {
            int ncol = nt * 16 + (lane & 15);
#pragma unroll
            for (int ks = 0; ks < 4; ++ks) {
                half8 bhi = *(const half8*)(WfHi + (size_t)ncol * DIM + ks * 32 + kg);
                half8 blo = *(const half8*)(WfLo + (size_t)ncol * DIM + ks * 32 + kg);
                ac2[nt] = __builtin_amdgcn_mfma_f32_16x16x32_f16(chi[ks], bhi, ac2[nt], 0, 0, 0);
                ac2[nt] = __builtin_amdgcn_mfma_f32_16x16x32_f16(clo[ks], bhi, ac2[nt], 0, 0, 0);
                ac2[nt] = __builtin_amdgcn_mfma_f32_16x16x32_f16(chi[ks], blo, ac2[nt], 0, 0, 0);
            }
        }
#pragma unroll
        for (int nt = 0; nt < 8; ++nt) {
            int col = nt * 16 + (lane & 15);
#pragma unroll
            for (int j = 0; j < 4; ++j) {
                int r = rglob + j;
                if (r < N) outF[(size_t)r * 768 + col] = fast_tanh(ac2[nt][j]);
            }
        }
    }
}

extern "C" void kernel_launch(void* const* d_in, const int* in_sizes, int n_in,
                              void* d_out, int out_size, void* d_ws, size_t ws_size,
                              hipStream_t stream)
{
    const float* x     = (const float*)d_in[0];
    const float* imp   = (const float*)d_in[1];
    const int*   eidx  = (const int*)d_in[2];
    const float* gamma = (const float*)d_in[3];
    const float* beta  = (const float*)d_in[4];
    const float* Wfc   = (const float*)d_in[5];
    const float* W[5]; const float* B[5];
    for (int i = 0; i < 5; ++i) {
        W[i] = (const float*)d_in[6 + 2 * i];
        B[i] = (const float*)d_in[7 + 2 * i];
    }
    float* out = (float*)d_out;

    const int N = in_sizes[0] / DIM;
    const int E = in_sizes[2] / 2;
    const int* src = eidx;
    const int* dst = eidx + E;

    char* ws = (char*)d_ws;
    size_t off = 0;
    auto alloc = [&](size_t b) -> char* {
        char* p = ws + off;
        off = (off + b + 255) & ~(size_t)255;
        return p;
    };
    short* hqA = (short*)alloc((size_t)N * DIM * 2);
    short* hqB = (short*)alloc((size_t)N * DIM * 2);
    _Float16* WtHi[6]; _Float16* WtLo[6];
    for (int i = 0; i < 6; ++i) {
        WtHi[i] = (_Float16*)alloc(DIM * DIM * 2);
        WtLo[i] = (_Float16*)alloc(DIM * DIM * 2);
    }
    int*   deg    = (int*)alloc((size_t)N * 4);
    int*   rstart = (int*)alloc((size_t)(N + 1) * 4);
    int*   cursor = (int*)alloc((size_t)N * 4);
    int*   csr    = (int*)alloc((size_t)E * 4);
    float* gsum   = (float*)alloc(128 * 4);
    float* gsq    = (float*)alloc(128 * 4);
    float* gmax   = (float*)alloc(128 * 4);
    float* scale  = (float*)alloc(128 * 4);
    float* shift  = (float*)alloc(128 * 4);
    float* q0     = (float*)alloc(2 * 4);
    int*   csum   = (int*)alloc(4096 * 4);

    hipMemsetAsync(gsum, 0, 128 * 4, stream);
    hipMemsetAsync(gsq,  0, 128 * 4, stream);
    hipMemsetAsync(gmax, 0, 128 * 4, stream);
    hipMemsetAsync(deg,  0, (size_t)N * 4, stream);

    // BN -> hq0 (int16, dynamic no-clip scale)
    k_stats<<<1024, 256, 0, stream>>>(x, imp, gsum, gsq, gmax, N);
    k_finalize<<<1, 128, 0, stream>>>(gsum, gsq, gmax, gamma, beta, scale, shift, q0, N);
    k_bn_quant<<<(N * 32 + 255) / 256, 256, 0, stream>>>(x, imp, scale, shift, q0, hqA, N * 32);

    // CSR
    k_hist<<<(E + 255) / 256, 256, 0, stream>>>(dst, deg, E);
    int nchunks = (N + 255) / 256;
    k_chunksum<<<nchunks, 256, 0, stream>>>(deg, csum, N);
    k_scanchunks<<<1, 512, 0, stream>>>(csum, rstart, nchunks, N);
    k_scanwithin<<<nchunks, 256, 0, stream>>>(deg, csum, rstart, cursor, N);
    k_scatter<<<(E + 255) / 256, 256, 0, stream>>>(src, dst, cursor, csr, E);

    // weights
    for (int i = 0; i < 5; ++i)
        k_wsplit<<<8, 256, 0, stream>>>(W[i], WtHi[i], WtLo[i]);
    k_wsplit<<<8, 256, 0, stream>>>(Wfc, WtHi[5], WtLo[5]);

    int grid = (N + 63) / 64;
    short* cur = hqA;
    short* nxt = hqB;
    for (int l = 0; l < 4; ++l) {
        k_layer<0><<<grid, 256, 0, stream>>>(cur, rstart, csr,
            (l == 0) ? (q0 + 1) : nullptr, INV_H,
            WtHi[l], WtLo[l], B[l], nullptr, nullptr,
            out + (size_t)l * DIM, nullptr, nxt, N);
        short* tmp = cur; cur = nxt; nxt = tmp;
    }
    // layer 5 + fused final FC
    k_layer<1><<<grid, 256, 0, stream>>>(cur, rstart, csr,
        nullptr, INV_H,
        WtHi[4], WtLo[4], B[4], WtHi[5], WtLo[5],
        out + (size_t)4 * DIM, out + (size_t)5 * DIM, nullptr, N);
}

// Round 7
// 993.897 us; speedup vs baseline: 1.6987x; 1.0364x over previous
//
#include <hip/hip_runtime.h>
#include <hip/hip_fp16.h>
#include <cstdint>
#include <cstddef>

#define DIM 128
#define BN_EPS_ 1e-5f

typedef _Float16 half8 __attribute__((ext_vector_type(8)));
typedef float floatx4 __attribute__((ext_vector_type(4)));
typedef short shortx8 __attribute__((ext_vector_type(8)));

#define SCALE_H 32768.f
#define INV_H   (1.f/32768.f)

__device__ __forceinline__ float fast_tanh(float x) {
    float t = __expf(2.f * x);
    return 1.f - 2.f / (t + 1.f);
}

__device__ __forceinline__ short quant(float v, float scale) {
    int q = __float2int_rn(v * scale);
    q = max(min(q, 32767), -32767);
    return (short)q;
}

// ---------------- BN stats: per-feature sum/sumsq/maxabs of h' = x*imp ----------------
__global__ __launch_bounds__(256) void k_stats(
    const float* __restrict__ x, const float* __restrict__ imp,
    float* __restrict__ gsum, float* __restrict__ gsq, float* __restrict__ gmax, int N)
{
    __shared__ float ls[256], lq[256], lm[256];
    int t = threadIdx.x;
    int f = t & 127;
    int rs = t >> 7;
    float s = 0.f, q = 0.f, m = 0.f;
    for (int r = blockIdx.x * 2 + rs; r < N; r += gridDim.x * 2) {
        float v = x[(size_t)r * DIM + f] * imp[r];
        s += v; q += v * v; m = fmaxf(m, fabsf(v));
    }
    ls[t] = s; lq[t] = q; lm[t] = m;
    __syncthreads();
    if (t < 128) {
        atomicAdd(&gsum[f], ls[t] + ls[t + 128]);
        atomicAdd(&gsq[f],  lq[t] + lq[t + 128]);
        float mm = fmaxf(lm[t], lm[t + 128]);
        atomicMax((int*)&gmax[f], __float_as_int(mm));  // valid: mm >= 0
    }
}

// scale/shift per column + global quant bound Q -> q0[0]=32766/Q, q0[1]=Q/32766
__global__ void k_finalize(const float* __restrict__ gsum, const float* __restrict__ gsq,
                           const float* __restrict__ gmax,
                           const float* __restrict__ gamma, const float* __restrict__ beta,
                           float* __restrict__ scale, float* __restrict__ shift,
                           float* __restrict__ q0, int N)
{
    __shared__ float sb[128];
    int f = threadIdx.x;
    float mean = gsum[f] / (float)N;
    float var  = gsq[f] / (float)N - mean * mean;
    var = fmaxf(var, 0.f);
    float sc = gamma[f] * rsqrtf(var + BN_EPS_);
    float sh = beta[f] - mean * sc;
    scale[f] = sc;
    shift[f] = sh;
    sb[f] = fabsf(sc) * gmax[f] + fabsf(sh);   // bound on |h0| in this column
    __syncthreads();
    for (int off = 64; off > 0; off >>= 1) {
        if (f < off) sb[f] = fmaxf(sb[f], sb[f + off]);
        __syncthreads();
    }
    if (f == 0) {
        float Q = fmaxf(sb[0], 1e-20f);
        q0[0] = 32766.f / Q;
        q0[1] = Q / 32766.f;
    }
}

// BN apply + quantize with dynamic scale -> hq0 (int16, exact bound: no clipping)
__global__ __launch_bounds__(256) void k_bn_quant(
    const float* __restrict__ x, const float* __restrict__ imp,
    const float* __restrict__ scale, const float* __restrict__ shift,
    const float* __restrict__ q0, short* __restrict__ hq0, int n32)
{
    int i = blockIdx.x * 256 + threadIdx.x;
    if (i >= n32) return;
    float qs = q0[0];
    int r = i >> 5, f4 = i & 31;
    float im = imp[r];
    float4 v  = ((const float4*)x)[i];
    float4 sc = ((const float4*)scale)[f4];
    float4 sh = ((const float4*)shift)[f4];
    short q[4];
    q[0] = quant(fmaf(v.x * im, sc.x, sh.x), qs);
    q[1] = quant(fmaf(v.y * im, sc.y, sh.y), qs);
    q[2] = quant(fmaf(v.z * im, sc.z, sh.z), qs);
    q[3] = quant(fmaf(v.w * im, sc.w, sh.w), qs);
    *(float2*)(hq0 + (size_t)i * 4) = *(float2*)q;
}

// ---------------- weight split: Wt{Hi,Lo}[n][k] from f32 W[k][n] ----------------
__global__ __launch_bounds__(256) void k_wsplit(const float* __restrict__ W,
                                               _Float16* __restrict__ WtHi,
                                               _Float16* __restrict__ WtLo)
{
    for (int e = blockIdx.x * 256 + threadIdx.x; e < DIM * DIM; e += gridDim.x * 256) {
        int k = e >> 7, n = e & 127;
        float w = W[e];
        _Float16 hi = (_Float16)w;
        _Float16 lo = (_Float16)(w - (float)hi);
        WtHi[n * DIM + k] = hi;
        WtLo[n * DIM + k] = lo;
    }
}

// ---------------- CSR build ----------------
__global__ void k_hist(const int* __restrict__ dst, int* __restrict__ deg, int E)
{
    int e = blockIdx.x * 256 + threadIdx.x;
    if (e < E) atomicAdd(&deg[dst[e]], 1);
}

__global__ __launch_bounds__(256) void k_chunksum(const int* __restrict__ deg, int* __restrict__ csum, int N)
{
    __shared__ int s[256];
    int t = threadIdx.x;
    int i = blockIdx.x * 256 + t;
    s[t] = (i < N) ? deg[i] : 0;
    __syncthreads();
    for (int off = 128; off > 0; off >>= 1) {
        if (t < off) s[t] += s[t + off];
        __syncthreads();
    }
    if (t == 0) csum[blockIdx.x] = s[0];
}

__global__ void k_scanchunks(int* __restrict__ csum, int* __restrict__ rstart, int nchunks, int N)
{
    __shared__ int s[512];
    int t = threadIdx.x;
    s[t] = (t < nchunks) ? csum[t] : 0;
    __syncthreads();
    for (int off = 1; off < 512; off <<= 1) {
        int add = (t >= off) ? s[t - off] : 0;
        __syncthreads();
        s[t] += add;
        __syncthreads();
    }
    if (t < nchunks) csum[t] = (t > 0) ? s[t - 1] : 0;
    if (t == 511) rstart[N] = s[511];
}

__global__ __launch_bounds__(256) void k_scanwithin(
    const int* __restrict__ deg, const int* __restrict__ csum,
    int* __restrict__ rstart, int* __restrict__ cursor, int N)
{
    __shared__ int s[256];
    int t = threadIdx.x;
    int i = blockIdx.x * 256 + t;
    int v = (i < N) ? deg[i] : 0;
    s[t] = v;
    __syncthreads();
    for (int off = 1; off < 256; off <<= 1) {
        int add = (t >= off) ? s[t - off] : 0;
        __syncthreads();
        s[t] += add;
        __syncthreads();
    }
    if (i < N) {
        int rs = csum[blockIdx.x] + s[t] - v;
        rstart[i] = rs;
        cursor[i] = rs;
    }
}

__global__ void k_scatter(const int* __restrict__ src, const int* __restrict__ dst,
                          int* __restrict__ cursor, int* __restrict__ csr, int E)
{
    int e = blockIdx.x * 256 + threadIdx.x;
    if (e < E) {
        int d = dst[e];
        int pos = atomicAdd(&cursor[d], 1);
        csr[pos] = src[e];
    }
}

// ---------------- fused GIN layer: gather(int16)+int32 sum -> LDS -> MFMA -> tanh ----------
// block = 128 threads = 32 nodes. Software-pipelined (double-buffered) gather.
// FINAL=1 additionally applies Wfc via LDS loopback.
template<int FINAL>
__global__ __launch_bounds__(128) void k_layer(
    const short* __restrict__ hqIn,
    const int* __restrict__ rstart, const int* __restrict__ csr,
    const float* __restrict__ invPtr, float invConst,
    const _Float16* __restrict__ WtHi, const _Float16* __restrict__ WtLo,
    const float* __restrict__ bias,
    const _Float16* __restrict__ WfHi, const _Float16* __restrict__ WfLo,
    float* __restrict__ outS,          // out + l*128, ld 768
    float* __restrict__ outF,          // out + 5*128 (FINAL only)
    short* __restrict__ hqOut,         // may be null
    int N)
{
    __shared__ float sA[32][132];      // 16.9 KB -> 9 blocks/CU
    int t = threadIdx.x;
    float inv = invPtr ? invPtr[0] : invConst;

    // ---- phase A: aggregate 32 nodes (16 lanes/node, 8 nodes/pass, 4 passes) ----
    {
        int l16 = t & 15;
        int sg  = t >> 4;              // 0..7
        const shortx8* base = (const shortx8*)hqIn;
#pragma unroll
        for (int pass = 0; pass < 4; ++pass) {
            int nl = pass * 8 + sg;
            int node = blockIdx.x * 32 + nl;
            float* dstp = &sA[nl][l16 * 8];
            if (node < N) {
                int beg = rstart[node], end = rstart[node + 1];
                shortx8 sv = base[(size_t)node * 16 + l16];
                int acc[8];
#pragma unroll
                for (int j = 0; j < 8; ++j) acc[j] = (int)sv[j];
                int e = beg;
                if (e + 4 <= end) {
                    // pipeline prologue: first 4 rows in flight
                    shortx8 b0 = base[(size_t)csr[e]     * 16 + l16];
                    shortx8 b1 = base[(size_t)csr[e + 1] * 16 + l16];
                    shortx8 b2 = base[(size_t)csr[e + 2] * 16 + l16];
                    shortx8 b3 = base[(size_t)csr[e + 3] * 16 + l16];
                    e += 4;
                    for (; e + 4 <= end; e += 4) {
                        // issue next 4 before consuming current 4 (8 in flight)
                        shortx8 c0 = base[(size_t)csr[e]     * 16 + l16];
                        shortx8 c1 = base[(size_t)csr[e + 1] * 16 + l16];
                        shortx8 c2 = base[(size_t)csr[e + 2] * 16 + l16];
                        shortx8 c3 = base[(size_t)csr[e + 3] * 16 + l16];
#pragma unroll
                        for (int j = 0; j < 8; ++j)
                            acc[j] += ((int)b0[j] + (int)b1[j]) + ((int)b2[j] + (int)b3[j]);
                        b0 = c0; b1 = c1; b2 = c2; b3 = c3;
                    }
#pragma unroll
                    for (int j = 0; j < 8; ++j)
                        acc[j] += ((int)b0[j] + (int)b1[j]) + ((int)b2[j] + (int)b3[j]);
                }
                for (; e < end; ++e) {
                    shortx8 v0 = base[(size_t)csr[e] * 16 + l16];
#pragma unroll
                    for (int j = 0; j < 8; ++j) acc[j] += (int)v0[j];
                }
#pragma unroll
                for (int j = 0; j < 8; ++j) dstp[j] = acc[j] * inv;
            } else {
#pragma unroll
                for (int j = 0; j < 8; ++j) dstp[j] = 0.f;
            }
        }
    }
    __syncthreads();

    // ---- phase B: per-wave 16x128 MFMA tile from LDS, hi/lo split ----
    int wave = t >> 6;                 // 0..1
    int lane = t & 63;
    int kg = (lane >> 4) * 8;
    int arowL = wave * 16 + (lane & 15);

    half8 ahi[4], alo[4];
#pragma unroll
    for (int ks = 0; ks < 4; ++ks) {
        float4 f0 = *(const float4*)&sA[arowL][ks * 32 + kg];
        float4 f1 = *(const float4*)&sA[arowL][ks * 32 + kg + 4];
        float fv[8] = {f0.x, f0.y, f0.z, f0.w, f1.x, f1.y, f1.z, f1.w};
#pragma unroll
        for (int j = 0; j < 8; ++j) {
            _Float16 h = (_Float16)fv[j];
            ahi[ks][j] = h;
            alo[ks][j] = (_Float16)(fv[j] - (float)h);
        }
    }

    floatx4 acc[8];
#pragma unroll
    for (int nt = 0; nt < 8; ++nt) acc[nt] = (floatx4){0.f, 0.f, 0.f, 0.f};
#pragma unroll
    for (int nt = 0; nt < 8; ++nt) {
        int ncol = nt * 16 + (lane & 15);
#pragma unroll
        for (int ks = 0; ks < 4; ++ks) {
            half8 bhi = *(const half8*)(WtHi + (size_t)ncol * DIM + ks * 32 + kg);
            half8 blo = *(const half8*)(WtLo + (size_t)ncol * DIM + ks * 32 + kg);
            acc[nt] = __builtin_amdgcn_mfma_f32_16x16x32_f16(ahi[ks], bhi, acc[nt], 0, 0, 0);
            acc[nt] = __builtin_amdgcn_mfma_f32_16x16x32_f16(alo[ks], bhi, acc[nt], 0, 0, 0);
            acc[nt] = __builtin_amdgcn_mfma_f32_16x16x32_f16(ahi[ks], blo, acc[nt], 0, 0, 0);
        }
    }

    int rbaseL = wave * 16 + (lane >> 4) * 4;
    int rglob = blockIdx.x * 32 + rbaseL;
    float tv[8][4];
#pragma unroll
    for (int nt = 0; nt < 8; ++nt) {
        int col = nt * 16 + (lane & 15);
        float bv = bias[col];
#pragma unroll
        for (int j = 0; j < 4; ++j) {
            float tt = fast_tanh(acc[nt][j] + bv);
            tv[nt][j] = tt;
            int r = rglob + j;
            if (r < N) {
                outS[(size_t)r * 768 + col] = tt;
                if (hqOut) hqOut[(size_t)r * DIM + col] = quant(tt, SCALE_H);
            }
        }
    }

    if (FINAL) {
        __syncthreads();   // all waves have consumed their sA a-frags
#pragma unroll
        for (int nt = 0; nt < 8; ++nt) {
            int col = nt * 16 + (lane & 15);
#pragma unroll
            for (int j = 0; j < 4; ++j)
                sA[rbaseL + j][col] = tv[nt][j];
        }
        __syncthreads();

        half8 chi[4], clo[4];
#pragma unroll
        for (int ks = 0; ks < 4; ++ks) {
            float4 f0 = *(const float4*)&sA[arowL][ks * 32 + kg];
            float4 f1 = *(const float4*)&sA[arowL][ks * 32 + kg + 4];
            float fv[8] = {f0.x, f0.y, f0.z, f0.w, f1.x, f1.y, f1.z, f1.w};
#pragma unroll
            for (int j = 0; j < 8; ++j) {
                _Float16 h = (_Float16)fv[j];
                chi[ks][j] = h;
                clo[ks][j] = (_Float16)(fv[j] - (float)h);
            }
        }
        floatx4 ac2[8];
#pragma unroll
        for (int nt = 0; nt < 8; ++nt) ac2[nt] = (floatx4){0.f, 0.f, 0.f, 0.f};
#pragma unroll
        for (int nt = 0; nt < 8; ++nt) {
            int ncol = nt * 16 + (lane & 15);
#pragma unroll
            for (int ks = 0; ks < 4; ++ks) {
                half8 bhi = *(const half8*)(WfHi + (size_t)ncol * DIM + ks * 32 + kg);
                half8 blo = *(const half8*)(WfLo + (size_t)ncol * DIM + ks * 32 + kg);
                ac2[nt] = __builtin_amdgcn_mfma_f32_16x16x32_f16(chi[ks], bhi, ac2[nt], 0, 0, 0);
                ac2[nt] = __builtin_amdgcn_mfma_f32_16x16x32_f16(clo[ks], bhi, ac2[nt], 0, 0, 0);
                ac2[nt] = __builtin_amdgcn_mfma_f32_16x16x32_f16(chi[ks], blo, ac2[nt], 0, 0, 0);
            }
        }
#pragma unroll
        for (int nt = 0; nt < 8; ++nt) {
            int col = nt * 16 + (lane & 15);
#pragma unroll
            for (int j = 0; j < 4; ++j) {
                int r = rglob + j;
                if (r < N) outF[(size_t)r * 768 + col] = fast_tanh(ac2[nt][j]);
            }
        }
    }
}

extern "C" void kernel_launch(void* const* d_in, const int* in_sizes, int n_in,
                              void* d_out, int out_size, void* d_ws, size_t ws_size,
                              hipStream_t stream)
{
    const float* x     = (const float*)d_in[0];
    const float* imp   = (const float*)d_in[1];
    const int*   eidx  = (const int*)d_in[2];
    const float* gamma = (const float*)d_in[3];
    const float* beta  = (const float*)d_in[4];
    const float* Wfc   = (const float*)d_in[5];
    const float* W[5]; const float* B[5];
    for (int i = 0; i < 5; ++i) {
        W[i] = (const float*)d_in[6 + 2 * i];
        B[i] = (const float*)d_in[7 + 2 * i];
    }
    float* out = (float*)d_out;

    const int N = in_sizes[0] / DIM;
    const int E = in_sizes[2] / 2;
    const int* src = eidx;
    const int* dst = eidx + E;

    char* ws = (char*)d_ws;
    size_t off = 0;
    auto alloc = [&](size_t b) -> char* {
        char* p = ws + off;
        off = (off + b + 255) & ~(size_t)255;
        return p;
    };
    short* hqA = (short*)alloc((size_t)N * DIM * 2);
    short* hqB = (short*)alloc((size_t)N * DIM * 2);
    _Float16* WtHi[6]; _Float16* WtLo[6];
    for (int i = 0; i < 6; ++i) {
        WtHi[i] = (_Float16*)alloc(DIM * DIM * 2);
        WtLo[i] = (_Float16*)alloc(DIM * DIM * 2);
    }
    int*   deg    = (int*)alloc((size_t)N * 4);
    int*   rstart = (int*)alloc((size_t)(N + 1) * 4);
    int*   cursor = (int*)alloc((size_t)N * 4);
    int*   csr    = (int*)alloc((size_t)E * 4);
    float* gsum   = (float*)alloc(128 * 4);
    float* gsq    = (float*)alloc(128 * 4);
    float* gmax   = (float*)alloc(128 * 4);
    float* scale  = (float*)alloc(128 * 4);
    float* shift  = (float*)alloc(128 * 4);
    float* q0     = (float*)alloc(2 * 4);
    int*   csum   = (int*)alloc(4096 * 4);

    hipMemsetAsync(gsum, 0, 128 * 4, stream);
    hipMemsetAsync(gsq,  0, 128 * 4, stream);
    hipMemsetAsync(gmax, 0, 128 * 4, stream);
    hipMemsetAsync(deg,  0, (size_t)N * 4, stream);

    // BN -> hq0 (int16, dynamic no-clip scale)
    k_stats<<<1024, 256, 0, stream>>>(x, imp, gsum, gsq, gmax, N);
    k_finalize<<<1, 128, 0, stream>>>(gsum, gsq, gmax, gamma, beta, scale, shift, q0, N);
    k_bn_quant<<<(N * 32 + 255) / 256, 256, 0, stream>>>(x, imp, scale, shift, q0, hqA, N * 32);

    // CSR
    k_hist<<<(E + 255) / 256, 256, 0, stream>>>(dst, deg, E);
    int nchunks = (N + 255) / 256;
    k_chunksum<<<nchunks, 256, 0, stream>>>(deg, csum, N);
    k_scanchunks<<<1, 512, 0, stream>>>(csum, rstart, nchunks, N);
    k_scanwithin<<<nchunks, 256, 0, stream>>>(deg, csum, rstart, cursor, N);
    k_scatter<<<(E + 255) / 256, 256, 0, stream>>>(src, dst, cursor, csr, E);

    // weights
    for (int i = 0; i < 5; ++i)
        k_wsplit<<<8, 256, 0, stream>>>(W[i], WtHi[i], WtLo[i]);
    k_wsplit<<<8, 256, 0, stream>>>(Wfc, WtHi[5], WtLo[5]);

    int grid = (N + 31) / 32;
    short* cur = hqA;
    short* nxt = hqB;
    for (int l = 0; l < 4; ++l) {
        k_layer<0><<<grid, 128, 0, stream>>>(cur, rstart, csr,
            (l == 0) ? (q0 + 1) : nullptr, INV_H,
            WtHi[l], WtLo[l], B[l], nullptr, nullptr,
            out + (size_t)l * DIM, nullptr, nxt, N);
        short* tmp = cur; cur = nxt; nxt = tmp;
    }
    // layer 5 + fused final FC
    k_layer<1><<<grid, 128, 0, stream>>>(cur, rstart, csr,
        nullptr, INV_H,
        WtHi[4], WtLo[4], B[4], WtHi[5], WtLo[5],
        out + (size_t)4 * DIM, out + (size_t)5 * DIM, nullptr, N);
}